// Round 10
// baseline (128.657 us; speedup 1.0000x reference)
//
#include <hip/hip_runtime.h>
#include <math.h>

typedef __attribute__((ext_vector_type(8))) short bf16x8;
typedef __attribute__((ext_vector_type(4))) float f32x4;
typedef unsigned short u16;

__device__ __forceinline__ unsigned short f2bf(float f) {
    unsigned u = __builtin_bit_cast(unsigned, f);
    u += 0x7fffu + ((u >> 16) & 1u);          // round-to-nearest-even
    return (unsigned short)(u >> 16);
}

// ---------------------------------------------------------------------------
// Prep 1: sin/cos table for all MZIs of all 3 meshes (+ pack P4 from W).
// trig[(s*128+L)*64 + t] = {cos th, sin th, cos phi, sin phi}
// P4: final real matrix [128 cols n][256 k] col-major bf16.
//   row(re,j) = (j>>4)*32 + (j&15), row(im,j) = +16
// ---------------------------------------------------------------------------
__global__ __launch_bounds__(128) void prep_trig_kernel(
    const float* __restrict__ mzi1, const float* __restrict__ mzi2,
    const float* __restrict__ mzi3, const float* __restrict__ W,
    float4* __restrict__ trig, u16* __restrict__ P4)
{
    const int b = blockIdx.x, t = threadIdx.x;
    if (b < 384) {
        if (t >= 64) return;
        const int s = b >> 7, L = b & 127;
        const float* mzi = (s == 0) ? mzi1 : ((s == 1) ? mzi2 : mzi3);
        const int start = L & 1;
        const int m = (128 - start) >> 1;
        float4 v = make_float4(1.f, 0.f, 1.f, 0.f);
        if (t < m) {
            const int off = (L >> 1) * 254 + start * 128 + 2 * t;
            float th = mzi[off], ph = mzi[off + 1];
            float st, ct, sp, cp;
            __sincosf(th, &st, &ct);
            __sincosf(ph, &sp, &cp);
            v = make_float4(ct, st, cp, sp);
        }
        trig[b * 64 + t] = v;
    } else {
        const int n = b - 384;           // output col 0..127
        const int j = t;                  // complex feature 0..127
        const int rre = ((j >> 4) * 32) + (j & 15);
        P4[n * 256 + rre]      = f2bf(W[n * 256 + j]);
        P4[n * 256 + rre + 16] = f2bf(W[n * 256 + j + 128]);
    }
}

// ---------------------------------------------------------------------------
// Prep 2: build row r of mesh s via register+shuffle layer composition,
// then pack to bf16 weight matrices in the block-16 interleaved real form.
// Thread t owns complex row elements j=2t, 2t+1.
// P1: [256 cols][128 k]; P2,P3: [256 cols][256 k]  (col-major, contiguous k)
// ---------------------------------------------------------------------------
__global__ __launch_bounds__(64) void build_pack_kernel(
    const float* __restrict__ inph,
    const float* __restrict__ outph1, const float* __restrict__ outph2,
    const float* __restrict__ outph3,
    const float4* __restrict__ trig,
    u16* __restrict__ P1, u16* __restrict__ P2, u16* __restrict__ P3)
{
    const int s = blockIdx.x >> 7, r = blockIdx.x & 127, t = threadIdx.x;
    const float4* tg = trig + s * 128 * 64;

    float2 a = make_float2(0.f, 0.f), b2 = make_float2(0.f, 0.f);
    if (s == 0) {
        float sp, cp; __sincosf(inph[r], &sp, &cp);
        if (2 * t == r)     a  = make_float2(cp, sp);
        if (2 * t + 1 == r) b2 = make_float2(cp, sp);
    } else {
        if (2 * t == r)     a.x  = 1.f;
        if (2 * t + 1 == r) b2.x = 1.f;
    }

    float4 tv[4];
    #pragma unroll
    for (int i = 0; i < 4; ++i) tv[i] = tg[i * 64 + t];

    #pragma unroll 4
    for (int L = 0; L < 128; ++L) {
        const float4 c = tv[L & 3];
        if (L < 124) tv[L & 3] = tg[(L + 4) * 64 + t];
        if ((L & 1) == 0) {
            // pair (u[2t], u[2t+1]) = (a, b2): thread-local
            float pr = c.x * (a.x * c.z - a.y * c.w) + c.y * b2.x;
            float pi = c.x * (a.x * c.w + a.y * c.z) + c.y * b2.y;
            float qr = c.y * a.x - c.x * (b2.x * c.z + b2.y * c.w);
            float qi = c.y * a.y - c.x * (b2.y * c.z - b2.x * c.w);
            a = make_float2(pr, pi); b2 = make_float2(qr, qi);
        } else {
            // pair (u[2t+1], u[2t+2]) = (b2_t, a_{t+1}); MZI t active for t<63
            float2 an;
            an.x = __shfl_down(a.x, 1); an.y = __shfl_down(a.y, 1);
            float pr = c.x * (b2.x * c.z - b2.y * c.w) + c.y * an.x;
            float pi = c.x * (b2.x * c.w + b2.y * c.z) + c.y * an.y;
            float qr = c.y * b2.x - c.x * (an.x * c.z + an.y * c.w);
            float qi = c.y * b2.y - c.x * (an.y * c.z - an.x * c.w);
            if (t < 63) b2 = make_float2(pr, pi);
            float2 qs;
            qs.x = __shfl_up(qr, 1); qs.y = __shfl_up(qi, 1);
            if (t >= 1) a = qs;
        }
    }

    const float* outph = (s == 0) ? outph1 : ((s == 1) ? outph2 : outph3);
    #pragma unroll
    for (int h = 0; h < 2; ++h) {
        const int j = 2 * t + h;
        float2 w = h ? b2 : a;
        float sp, cp; __sincosf(outph[j], &sp, &cp);
        const float wr = w.x * cp - w.y * sp;
        const float wi = w.x * sp + w.y * cp;
        const int cre = ((j >> 4) * 32) + (j & 15);
        if (s == 0) {
            P1[cre * 128 + r]        = f2bf(wr);
            P1[(cre + 16) * 128 + r] = f2bf(wi);
        } else {
            u16* P = (s == 1) ? P2 : P3;
            const int rre = ((r >> 4) * 32) + (r & 15);
            P[cre * 256 + rre]             = f2bf(wr);
            P[cre * 256 + rre + 16]        = f2bf(-wi);
            P[(cre + 16) * 256 + rre]      = f2bf(wi);
            P[(cre + 16) * 256 + rre + 16] = f2bf(wr);
        }
    }
}

// ---------------------------------------------------------------------------
// Main fused kernel. 256 threads = 4 waves (1 M x 4 N), 32 batch rows/block.
// Wave tile 32x64 (mt=2): acc = 32 regs (vs 64 at 64x64) -> minimum live set
// ~56 regs, fits the __launch_bounds__(256,4) 128-reg budget WITHOUT spill
// (R7 spilled at this bound because acc=64 pushed min-live to ~96).
// 4 independent blocks/CU = 16 waves/CU for latency hiding; zA = 16KB.
// Numerics identical to R9 (f2bf + IEEE div).
// ---------------------------------------------------------------------------
__global__ __launch_bounds__(256, 4) void ficonn_mfma_kernel(
    const float* __restrict__ x,
    const u16* __restrict__ P1, const u16* __restrict__ P2,
    const u16* __restrict__ P3, const u16* __restrict__ P4,
    const float* __restrict__ al1, const float* __restrict__ be1,
    const float* __restrict__ al2, const float* __restrict__ be2,
    const float* __restrict__ bias, float* __restrict__ out)
{
    __shared__ __align__(16) char zA[16384];   // [32 rows][256 cols] bf16, swizzled

    const int tid  = threadIdx.x;
    const int lane = tid & 63;
    const int wn   = tid >> 6;        // 0..3 (N-split)
    const int l16  = lane & 15;
    const int kg   = lane >> 4;
    const int nb   = wn * 64;
    const size_t rowBase = (size_t)blockIdx.x * 32;

    float av1[2], bv1[2], av2[2], bv2[2];
    #pragma unroll
    for (int u = 0; u < 2; ++u) {
        const int j = wn * 32 + u * 16 + l16;
        av1[u] = 0.5f * fminf(fmaxf(al1[j], 0.f), 10.f);
        bv1[u] = fminf(fmaxf(be1[j], 0.f), 10.f);
        av2[u] = 0.5f * fminf(fmaxf(al2[j], 0.f), 10.f);
        bv2[u] = fminf(fmaxf(be2[j], 0.f), 10.f);
    }

    // ---- stage x tile (32 rows x 128 cols fp32) into zA as bf16, coalesced --
    {
        const float4* xg = (const float4*)(x + rowBase * 128);
        #pragma unroll
        for (int i = 0; i < 4; ++i) {
            const int idx = tid + i * 256;        // 0..1023
            const int row = idx >> 5;             // 32 float4 per row
            const int c4  = idx & 31;
            float4 f = xg[idx];
            uint2 v;
            v.x = (unsigned)f2bf(f.x) | ((unsigned)f2bf(f.y) << 16);
            v.y = (unsigned)f2bf(f.z) | ((unsigned)f2bf(f.w) << 16);
            const unsigned byte = ((unsigned)(row * 512 + c4 * 8)) ^ ((unsigned)(row & 31) << 4);
            *(uint2*)(zA + byte) = v;
        }
    }
    __syncthreads();

    f32x4 acc[2][4];

    // ================= stage 1: A = zA (x bf16), B = P1, K=128 ==============
    #pragma unroll
    for (int mt = 0; mt < 2; ++mt)
        #pragma unroll
        for (int nt = 0; nt < 4; ++nt) acc[mt][nt] = (f32x4){0.f, 0.f, 0.f, 0.f};

    #pragma unroll
    for (int ks = 0; ks < 4; ++ks) {
        const int k0 = ks * 32 + kg * 8;
        bf16x8 A[2];
        #pragma unroll
        for (int mt = 0; mt < 2; ++mt) {
            const int row = mt * 16 + l16;
            const unsigned byte = ((unsigned)(row * 512 + k0 * 2)) ^ ((unsigned)(row & 31) << 4);
            A[mt] = *(const bf16x8*)(zA + byte);
        }
        #pragma unroll
        for (int nt = 0; nt < 4; ++nt) {
            bf16x8 Bf = *(const bf16x8*)&P1[(nb + nt * 16 + l16) * 128 + k0];
            #pragma unroll
            for (int mt = 0; mt < 2; ++mt)
                acc[mt][nt] = __builtin_amdgcn_mfma_f32_16x16x32_bf16(A[mt], Bf, acc[mt][nt], 0, 0, 0);
        }
    }
    __syncthreads();   // all x reads done before overwrite

    // nofu1 + store to zA
    #pragma unroll
    for (int mt = 0; mt < 2; ++mt)
        #pragma unroll
        for (int u = 0; u < 2; ++u)
            #pragma unroll
            for (int r = 0; r < 4; ++r) {
                float re = acc[mt][2 * u][r], im = acc[mt][2 * u + 1][r];
                float I = fmaf(re, re, fmaf(im, im, 1e-8f));
                float fct = __expf(-av1[u] / fmaf(bv1[u], I, 1.f));
                re *= fct; im *= fct;
                const int row = mt * 16 + kg * 4 + r;
                const int colRe = nb + u * 32 + l16;
                const unsigned sw = (unsigned)(row & 31) << 4;
                *(u16*)(zA + (((unsigned)(row * 512 + colRe * 2)) ^ sw)) = f2bf(re);
                *(u16*)(zA + (((unsigned)(row * 512 + (colRe + 16) * 2)) ^ sw)) = f2bf(im);
            }
    __syncthreads();

    // ================= stage 2: A = zA, B = P2, K=256 =======================
    #pragma unroll
    for (int mt = 0; mt < 2; ++mt)
        #pragma unroll
        for (int nt = 0; nt < 4; ++nt) acc[mt][nt] = (f32x4){0.f, 0.f, 0.f, 0.f};

    #pragma unroll
    for (int ks = 0; ks < 8; ++ks) {
        const int k0 = ks * 32 + kg * 8;
        bf16x8 A[2];
        #pragma unroll
        for (int mt = 0; mt < 2; ++mt) {
            const int row = mt * 16 + l16;
            const unsigned byte = ((unsigned)(row * 512 + k0 * 2)) ^ ((unsigned)(row & 31) << 4);
            A[mt] = *(const bf16x8*)(zA + byte);
        }
        #pragma unroll
        for (int nt = 0; nt < 4; ++nt) {
            bf16x8 Bf = *(const bf16x8*)&P2[(nb + nt * 16 + l16) * 256 + k0];
            #pragma unroll
            for (int mt = 0; mt < 2; ++mt)
                acc[mt][nt] = __builtin_amdgcn_mfma_f32_16x16x32_bf16(A[mt], Bf, acc[mt][nt], 0, 0, 0);
        }
    }
    __syncthreads();   // all zA reads done before overwrite

    // nofu2 + store to zA
    #pragma unroll
    for (int mt = 0; mt < 2; ++mt)
        #pragma unroll
        for (int u = 0; u < 2; ++u)
            #pragma unroll
            for (int r = 0; r < 4; ++r) {
                float re = acc[mt][2 * u][r], im = acc[mt][2 * u + 1][r];
                float I = fmaf(re, re, fmaf(im, im, 1e-8f));
                float fct = __expf(-av2[u] / fmaf(bv2[u], I, 1.f));
                re *= fct; im *= fct;
                const int row = mt * 16 + kg * 4 + r;
                const int colRe = nb + u * 32 + l16;
                const unsigned sw = (unsigned)(row & 31) << 4;
                *(u16*)(zA + (((unsigned)(row * 512 + colRe * 2)) ^ sw)) = f2bf(re);
                *(u16*)(zA + (((unsigned)(row * 512 + (colRe + 16) * 2)) ^ sw)) = f2bf(im);
            }
    __syncthreads();

    // ================= stage 3: A = zA, B = P3, K=256 (no nofu) =============
    #pragma unroll
    for (int mt = 0; mt < 2; ++mt)
        #pragma unroll
        for (int nt = 0; nt < 4; ++nt) acc[mt][nt] = (f32x4){0.f, 0.f, 0.f, 0.f};

    #pragma unroll
    for (int ks = 0; ks < 8; ++ks) {
        const int k0 = ks * 32 + kg * 8;
        bf16x8 A[2];
        #pragma unroll
        for (int mt = 0; mt < 2; ++mt) {
            const int row = mt * 16 + l16;
            const unsigned byte = ((unsigned)(row * 512 + k0 * 2)) ^ ((unsigned)(row & 31) << 4);
            A[mt] = *(const bf16x8*)(zA + byte);
        }
        #pragma unroll
        for (int nt = 0; nt < 4; ++nt) {
            bf16x8 Bf = *(const bf16x8*)&P3[(nb + nt * 16 + l16) * 256 + k0];
            #pragma unroll
            for (int mt = 0; mt < 2; ++mt)
                acc[mt][nt] = __builtin_amdgcn_mfma_f32_16x16x32_bf16(A[mt], Bf, acc[mt][nt], 0, 0, 0);
        }
    }
    __syncthreads();

    // store z3 (plain) to zA
    #pragma unroll
    for (int mt = 0; mt < 2; ++mt)
        #pragma unroll
        for (int u = 0; u < 2; ++u)
            #pragma unroll
            for (int r = 0; r < 4; ++r) {
                const int row = mt * 16 + kg * 4 + r;
                const int colRe = nb + u * 32 + l16;
                const unsigned sw = (unsigned)(row & 31) << 4;
                *(u16*)(zA + (((unsigned)(row * 512 + colRe * 2)) ^ sw)) = f2bf(acc[mt][2 * u][r]);
                *(u16*)(zA + (((unsigned)(row * 512 + (colRe + 16) * 2)) ^ sw)) = f2bf(acc[mt][2 * u + 1][r]);
            }
    __syncthreads();

    // ================= final: A = zA, B = P4 [128 cols][256 k], 32 cols/wave =
    f32x4 facc[2][2];
    #pragma unroll
    for (int mt = 0; mt < 2; ++mt)
        #pragma unroll
        for (int nt = 0; nt < 2; ++nt) facc[mt][nt] = (f32x4){0.f, 0.f, 0.f, 0.f};

    const int nb2 = wn * 32;
    #pragma unroll
    for (int ks = 0; ks < 8; ++ks) {
        const int k0 = ks * 32 + kg * 8;
        bf16x8 A[2];
        #pragma unroll
        for (int mt = 0; mt < 2; ++mt) {
            const int row = mt * 16 + l16;
            const unsigned byte = ((unsigned)(row * 512 + k0 * 2)) ^ ((unsigned)(row & 31) << 4);
            A[mt] = *(const bf16x8*)(zA + byte);
        }
        #pragma unroll
        for (int nt = 0; nt < 2; ++nt) {
            bf16x8 Bf = *(const bf16x8*)&P4[(nb2 + nt * 16 + l16) * 256 + k0];
            #pragma unroll
            for (int mt = 0; mt < 2; ++mt)
                facc[mt][nt] = __builtin_amdgcn_mfma_f32_16x16x32_bf16(A[mt], Bf, facc[mt][nt], 0, 0, 0);
        }
    }

    const float bcol0 = bias[nb2 + l16];
    const float bcol1 = bias[nb2 + 16 + l16];
    #pragma unroll
    for (int mt = 0; mt < 2; ++mt)
        #pragma unroll
        for (int r = 0; r < 4; ++r) {
            const size_t row = rowBase + mt * 16 + kg * 4 + r;
            out[row * 128 + nb2 + l16]      = facc[mt][0][r] + bcol0;
            out[row * 128 + nb2 + 16 + l16] = facc[mt][1][r] + bcol1;
        }
}

extern "C" void kernel_launch(void* const* d_in, const int* in_sizes, int n_in,
                              void* d_out, int out_size, void* d_ws, size_t ws_size,
                              hipStream_t stream)
{
    const float* x      = (const float*)d_in[0];
    const float* inph   = (const float*)d_in[1];
    const float* mzi1   = (const float*)d_in[2];
    const float* outph1 = (const float*)d_in[3];
    const float* alpha1 = (const float*)d_in[4];
    const float* beta1  = (const float*)d_in[5];
    const float* mzi2   = (const float*)d_in[6];
    const float* outph2 = (const float*)d_in[7];
    const float* alpha2 = (const float*)d_in[8];
    const float* beta2  = (const float*)d_in[9];
    const float* mzi3   = (const float*)d_in[10];
    const float* outph3 = (const float*)d_in[11];
    const float* W      = (const float*)d_in[12];
    const float* bias   = (const float*)d_in[13];

    const int B = in_sizes[0] / 128;

    // ws layout
    float4* trig = (float4*)d_ws;                          // 3*128*64*16 = 393216 B
    u16* P1 = (u16*)((char*)d_ws + 393216);                // 65536 B
    u16* P2 = P1 + 32768;                                  // 131072 B
    u16* P3 = P2 + 65536;                                  // 131072 B
    u16* P4 = P3 + 65536;                                  // 65536 B

    prep_trig_kernel<<<512, 128, 0, stream>>>(mzi1, mzi2, mzi3, W, trig, P4);
    build_pack_kernel<<<384, 64, 0, stream>>>(inph, outph1, outph2, outph3, trig, P1, P2, P3);
    ficonn_mfma_kernel<<<B / 32, 256, 0, stream>>>(
        x, P1, P2, P3, P4, alpha1, beta1, alpha2, beta2, bias, (float*)d_out);
}

// Round 11
// 91.984 us; speedup vs baseline: 1.3987x; 1.3987x over previous
//
#include <hip/hip_runtime.h>
#include <math.h>

typedef __attribute__((ext_vector_type(8))) short bf16x8;
typedef __attribute__((ext_vector_type(4))) float f32x4;
typedef unsigned short u16;

__device__ __forceinline__ unsigned short f2bf(float f) {
    unsigned u = __builtin_bit_cast(unsigned, f);
    u += 0x7fffu + ((u >> 16) & 1u);          // round-to-nearest-even
    return (unsigned short)(u >> 16);
}

// ---------------------------------------------------------------------------
// Prep 1: sin/cos table for all MZIs of all 3 meshes (+ pack P4 from W).
// ---------------------------------------------------------------------------
__global__ __launch_bounds__(128) void prep_trig_kernel(
    const float* __restrict__ mzi1, const float* __restrict__ mzi2,
    const float* __restrict__ mzi3, const float* __restrict__ W,
    float4* __restrict__ trig, u16* __restrict__ P4)
{
    const int b = blockIdx.x, t = threadIdx.x;
    if (b < 384) {
        if (t >= 64) return;
        const int s = b >> 7, L = b & 127;
        const float* mzi = (s == 0) ? mzi1 : ((s == 1) ? mzi2 : mzi3);
        const int start = L & 1;
        const int m = (128 - start) >> 1;
        float4 v = make_float4(1.f, 0.f, 1.f, 0.f);
        if (t < m) {
            const int off = (L >> 1) * 254 + start * 128 + 2 * t;
            float th = mzi[off], ph = mzi[off + 1];
            float st, ct, sp, cp;
            __sincosf(th, &st, &ct);
            __sincosf(ph, &sp, &cp);
            v = make_float4(ct, st, cp, sp);
        }
        trig[b * 64 + t] = v;
    } else {
        const int n = b - 384;           // output col 0..127
        const int j = t;                  // complex feature 0..127
        const int rre = ((j >> 4) * 32) + (j & 15);
        P4[n * 256 + rre]      = f2bf(W[n * 256 + j]);
        P4[n * 256 + rre + 16] = f2bf(W[n * 256 + j + 128]);
    }
}

// ---------------------------------------------------------------------------
// Prep 2: build row r of mesh s via register+shuffle layer composition,
// then pack to bf16 weight matrices in the block-16 interleaved real form.
// ---------------------------------------------------------------------------
__global__ __launch_bounds__(64) void build_pack_kernel(
    const float* __restrict__ inph,
    const float* __restrict__ outph1, const float* __restrict__ outph2,
    const float* __restrict__ outph3,
    const float4* __restrict__ trig,
    u16* __restrict__ P1, u16* __restrict__ P2, u16* __restrict__ P3)
{
    const int s = blockIdx.x >> 7, r = blockIdx.x & 127, t = threadIdx.x;
    const float4* tg = trig + s * 128 * 64;

    float2 a = make_float2(0.f, 0.f), b2 = make_float2(0.f, 0.f);
    if (s == 0) {
        float sp, cp; __sincosf(inph[r], &sp, &cp);
        if (2 * t == r)     a  = make_float2(cp, sp);
        if (2 * t + 1 == r) b2 = make_float2(cp, sp);
    } else {
        if (2 * t == r)     a.x  = 1.f;
        if (2 * t + 1 == r) b2.x = 1.f;
    }

    float4 tv[4];
    #pragma unroll
    for (int i = 0; i < 4; ++i) tv[i] = tg[i * 64 + t];

    #pragma unroll 4
    for (int L = 0; L < 128; ++L) {
        const float4 c = tv[L & 3];
        if (L < 124) tv[L & 3] = tg[(L + 4) * 64 + t];
        if ((L & 1) == 0) {
            float pr = c.x * (a.x * c.z - a.y * c.w) + c.y * b2.x;
            float pi = c.x * (a.x * c.w + a.y * c.z) + c.y * b2.y;
            float qr = c.y * a.x - c.x * (b2.x * c.z + b2.y * c.w);
            float qi = c.y * a.y - c.x * (b2.y * c.z - b2.x * c.w);
            a = make_float2(pr, pi); b2 = make_float2(qr, qi);
        } else {
            float2 an;
            an.x = __shfl_down(a.x, 1); an.y = __shfl_down(a.y, 1);
            float pr = c.x * (b2.x * c.z - b2.y * c.w) + c.y * an.x;
            float pi = c.x * (b2.x * c.w + b2.y * c.z) + c.y * an.y;
            float qr = c.y * b2.x - c.x * (an.x * c.z + an.y * c.w);
            float qi = c.y * b2.y - c.x * (an.y * c.z - an.x * c.w);
            if (t < 63) b2 = make_float2(pr, pi);
            float2 qs;
            qs.x = __shfl_up(qr, 1); qs.y = __shfl_up(qi, 1);
            if (t >= 1) a = qs;
        }
    }

    const float* outph = (s == 0) ? outph1 : ((s == 1) ? outph2 : outph3);
    #pragma unroll
    for (int h = 0; h < 2; ++h) {
        const int j = 2 * t + h;
        float2 w = h ? b2 : a;
        float sp, cp; __sincosf(outph[j], &sp, &cp);
        const float wr = w.x * cp - w.y * sp;
        const float wi = w.x * sp + w.y * cp;
        const int cre = ((j >> 4) * 32) + (j & 15);
        if (s == 0) {
            P1[cre * 128 + r]        = f2bf(wr);
            P1[(cre + 16) * 128 + r] = f2bf(wi);
        } else {
            u16* P = (s == 1) ? P2 : P3;
            const int rre = ((r >> 4) * 32) + (r & 15);
            P[cre * 256 + rre]             = f2bf(wr);
            P[cre * 256 + rre + 16]        = f2bf(-wi);
            P[(cre + 16) * 256 + rre]      = f2bf(wi);
            P[(cre + 16) * 256 + rre + 16] = f2bf(wr);
        }
    }
}

// ---------------------------------------------------------------------------
// Main fused kernel. R9 shell (93us, spill-free): 256 threads = 4 waves
// (1M x 4N), 64 batch rows/block, wave tile 64x64, (256,2) = 256-reg budget,
// 2 independent blocks/CU, zA 32KB swizzled.
// R11 change: B-fragments batched 16-deep into a static-indexed register
// array BEFORE each 4-ks MFMA cluster -> one L2 latency amortizes over 64
// MFMAs instead of stalling every 4 (compiler alone stopped hoisting at 124
// VGPRs; source-level batching forces the deep pipeline; all indices
// compile-time so the array stays in registers).
// Reg math: acc 64 + Bv 64 + A 16 + misc ~ 170 < 256 -> no spill expected.
// ---------------------------------------------------------------------------
__global__ __launch_bounds__(256, 2) void ficonn_mfma_kernel(
    const float* __restrict__ x,
    const u16* __restrict__ P1, const u16* __restrict__ P2,
    const u16* __restrict__ P3, const u16* __restrict__ P4,
    const float* __restrict__ al1, const float* __restrict__ be1,
    const float* __restrict__ al2, const float* __restrict__ be2,
    const float* __restrict__ bias, float* __restrict__ out)
{
    __shared__ __align__(16) char zA[32768];   // [64 rows][256 cols] bf16, swizzled

    const int tid  = threadIdx.x;
    const int lane = tid & 63;
    const int wn   = tid >> 6;        // 0..3 (N-split)
    const int l16  = lane & 15;
    const int kg   = lane >> 4;
    const int nb   = wn * 64;
    const size_t rowBase = (size_t)blockIdx.x * 64;

    float av1[2], bv1[2], av2[2], bv2[2];
    #pragma unroll
    for (int u = 0; u < 2; ++u) {
        const int j = wn * 32 + u * 16 + l16;
        av1[u] = 0.5f * fminf(fmaxf(al1[j], 0.f), 10.f);
        bv1[u] = fminf(fmaxf(be1[j], 0.f), 10.f);
        av2[u] = 0.5f * fminf(fmaxf(al2[j], 0.f), 10.f);
        bv2[u] = fminf(fmaxf(be2[j], 0.f), 10.f);
    }

    // ---- stage x tile (64 rows x 128 cols fp32) into zA as bf16, coalesced --
    {
        const float4* xg = (const float4*)(x + rowBase * 128);
        #pragma unroll
        for (int i = 0; i < 8; ++i) {
            const int idx = tid + i * 256;        // 0..2047
            const int row = idx >> 5;             // 32 float4 per row
            const int c4  = idx & 31;
            float4 f = xg[idx];
            uint2 v;
            v.x = (unsigned)f2bf(f.x) | ((unsigned)f2bf(f.y) << 16);
            v.y = (unsigned)f2bf(f.z) | ((unsigned)f2bf(f.w) << 16);
            const unsigned byte = ((unsigned)(row * 512 + c4 * 8)) ^ ((unsigned)(row & 31) << 4);
            *(uint2*)(zA + byte) = v;
        }
    }
    __syncthreads();

    f32x4 acc[4][4];

    // ================= stage 1: A = zA (x bf16), B = P1, K=128 ==============
    #pragma unroll
    for (int mt = 0; mt < 4; ++mt)
        #pragma unroll
        for (int nt = 0; nt < 4; ++nt) acc[mt][nt] = (f32x4){0.f, 0.f, 0.f, 0.f};

    {
        // one 16-deep B batch covers the whole K=128 stage
        bf16x8 Bv[16];
        #pragma unroll
        for (int ksl = 0; ksl < 4; ++ksl)
            #pragma unroll
            for (int nt = 0; nt < 4; ++nt)
                Bv[ksl * 4 + nt] = *(const bf16x8*)&P1[(nb + nt * 16 + l16) * 128 + ksl * 32 + kg * 8];

        #pragma unroll
        for (int ksl = 0; ksl < 4; ++ksl) {
            const int k0 = ksl * 32 + kg * 8;
            bf16x8 A[4];
            #pragma unroll
            for (int mt = 0; mt < 4; ++mt) {
                const int row = mt * 16 + l16;
                const unsigned byte = ((unsigned)(row * 512 + k0 * 2)) ^ ((unsigned)(row & 31) << 4);
                A[mt] = *(const bf16x8*)(zA + byte);
            }
            #pragma unroll
            for (int nt = 0; nt < 4; ++nt)
                #pragma unroll
                for (int mt = 0; mt < 4; ++mt)
                    acc[mt][nt] = __builtin_amdgcn_mfma_f32_16x16x32_bf16(A[mt], Bv[ksl * 4 + nt], acc[mt][nt], 0, 0, 0);
        }
    }
    __syncthreads();   // all x reads done before overwrite

    // nofu1 + store to zA
    #pragma unroll
    for (int mt = 0; mt < 4; ++mt)
        #pragma unroll
        for (int u = 0; u < 2; ++u)
            #pragma unroll
            for (int r = 0; r < 4; ++r) {
                float re = acc[mt][2 * u][r], im = acc[mt][2 * u + 1][r];
                float I = fmaf(re, re, fmaf(im, im, 1e-8f));
                float fct = __expf(-av1[u] / fmaf(bv1[u], I, 1.f));
                re *= fct; im *= fct;
                const int row = mt * 16 + kg * 4 + r;
                const int colRe = nb + u * 32 + l16;
                const unsigned sw = (unsigned)(row & 31) << 4;
                *(u16*)(zA + (((unsigned)(row * 512 + colRe * 2)) ^ sw)) = f2bf(re);
                *(u16*)(zA + (((unsigned)(row * 512 + (colRe + 16) * 2)) ^ sw)) = f2bf(im);
            }
    __syncthreads();

    // ================= stage 2: A = zA, B = P2, K=256 =======================
    #pragma unroll
    for (int mt = 0; mt < 4; ++mt)
        #pragma unroll
        for (int nt = 0; nt < 4; ++nt) acc[mt][nt] = (f32x4){0.f, 0.f, 0.f, 0.f};

    #pragma unroll
    for (int ksb = 0; ksb < 2; ++ksb) {
        bf16x8 Bv[16];
        #pragma unroll
        for (int ksl = 0; ksl < 4; ++ksl)
            #pragma unroll
            for (int nt = 0; nt < 4; ++nt)
                Bv[ksl * 4 + nt] = *(const bf16x8*)&P2[(nb + nt * 16 + l16) * 256 + (ksb * 4 + ksl) * 32 + kg * 8];

        #pragma unroll
        for (int ksl = 0; ksl < 4; ++ksl) {
            const int k0 = (ksb * 4 + ksl) * 32 + kg * 8;
            bf16x8 A[4];
            #pragma unroll
            for (int mt = 0; mt < 4; ++mt) {
                const int row = mt * 16 + l16;
                const unsigned byte = ((unsigned)(row * 512 + k0 * 2)) ^ ((unsigned)(row & 31) << 4);
                A[mt] = *(const bf16x8*)(zA + byte);
            }
            #pragma unroll
            for (int nt = 0; nt < 4; ++nt)
                #pragma unroll
                for (int mt = 0; mt < 4; ++mt)
                    acc[mt][nt] = __builtin_amdgcn_mfma_f32_16x16x32_bf16(A[mt], Bv[ksl * 4 + nt], acc[mt][nt], 0, 0, 0);
        }
    }
    __syncthreads();   // all zA reads done before overwrite

    // nofu2 + store to zA
    #pragma unroll
    for (int mt = 0; mt < 4; ++mt)
        #pragma unroll
        for (int u = 0; u < 2; ++u)
            #pragma unroll
            for (int r = 0; r < 4; ++r) {
                float re = acc[mt][2 * u][r], im = acc[mt][2 * u + 1][r];
                float I = fmaf(re, re, fmaf(im, im, 1e-8f));
                float fct = __expf(-av2[u] / fmaf(bv2[u], I, 1.f));
                re *= fct; im *= fct;
                const int row = mt * 16 + kg * 4 + r;
                const int colRe = nb + u * 32 + l16;
                const unsigned sw = (unsigned)(row & 31) << 4;
                *(u16*)(zA + (((unsigned)(row * 512 + colRe * 2)) ^ sw)) = f2bf(re);
                *(u16*)(zA + (((unsigned)(row * 512 + (colRe + 16) * 2)) ^ sw)) = f2bf(im);
            }
    __syncthreads();

    // ================= stage 3: A = zA, B = P3, K=256 (no nofu) =============
    #pragma unroll
    for (int mt = 0; mt < 4; ++mt)
        #pragma unroll
        for (int nt = 0; nt < 4; ++nt) acc[mt][nt] = (f32x4){0.f, 0.f, 0.f, 0.f};

    #pragma unroll
    for (int ksb = 0; ksb < 2; ++ksb) {
        bf16x8 Bv[16];
        #pragma unroll
        for (int ksl = 0; ksl < 4; ++ksl)
            #pragma unroll
            for (int nt = 0; nt < 4; ++nt)
                Bv[ksl * 4 + nt] = *(const bf16x8*)&P3[(nb + nt * 16 + l16) * 256 + (ksb * 4 + ksl) * 32 + kg * 8];

        #pragma unroll
        for (int ksl = 0; ksl < 4; ++ksl) {
            const int k0 = (ksb * 4 + ksl) * 32 + kg * 8;
            bf16x8 A[4];
            #pragma unroll
            for (int mt = 0; mt < 4; ++mt) {
                const int row = mt * 16 + l16;
                const unsigned byte = ((unsigned)(row * 512 + k0 * 2)) ^ ((unsigned)(row & 31) << 4);
                A[mt] = *(const bf16x8*)(zA + byte);
            }
            #pragma unroll
            for (int nt = 0; nt < 4; ++nt)
                #pragma unroll
                for (int mt = 0; mt < 4; ++mt)
                    acc[mt][nt] = __builtin_amdgcn_mfma_f32_16x16x32_bf16(A[mt], Bv[ksl * 4 + nt], acc[mt][nt], 0, 0, 0);
        }
    }
    __syncthreads();

    // store z3 (plain) to zA
    #pragma unroll
    for (int mt = 0; mt < 4; ++mt)
        #pragma unroll
        for (int u = 0; u < 2; ++u)
            #pragma unroll
            for (int r = 0; r < 4; ++r) {
                const int row = mt * 16 + kg * 4 + r;
                const int colRe = nb + u * 32 + l16;
                const unsigned sw = (unsigned)(row & 31) << 4;
                *(u16*)(zA + (((unsigned)(row * 512 + colRe * 2)) ^ sw)) = f2bf(acc[mt][2 * u][r]);
                *(u16*)(zA + (((unsigned)(row * 512 + (colRe + 16) * 2)) ^ sw)) = f2bf(acc[mt][2 * u + 1][r]);
            }
    __syncthreads();

    // ================= final: A = zA, B = P4 [128 cols][256 k], 32 cols/wave =
    f32x4 facc[4][2];
    #pragma unroll
    for (int mt = 0; mt < 4; ++mt)
        #pragma unroll
        for (int nt = 0; nt < 2; ++nt) facc[mt][nt] = (f32x4){0.f, 0.f, 0.f, 0.f};

    const int nb2 = wn * 32;
    #pragma unroll
    for (int ksb = 0; ksb < 2; ++ksb) {
        bf16x8 Bv[8];
        #pragma unroll
        for (int ksl = 0; ksl < 4; ++ksl)
            #pragma unroll
            for (int nt = 0; nt < 2; ++nt)
                Bv[ksl * 2 + nt] = *(const bf16x8*)&P4[(nb2 + nt * 16 + l16) * 256 + (ksb * 4 + ksl) * 32 + kg * 8];

        #pragma unroll
        for (int ksl = 0; ksl < 4; ++ksl) {
            const int k0 = (ksb * 4 + ksl) * 32 + kg * 8;
            bf16x8 A[4];
            #pragma unroll
            for (int mt = 0; mt < 4; ++mt) {
                const int row = mt * 16 + l16;
                const unsigned byte = ((unsigned)(row * 512 + k0 * 2)) ^ ((unsigned)(row & 31) << 4);
                A[mt] = *(const bf16x8*)(zA + byte);
            }
            #pragma unroll
            for (int nt = 0; nt < 2; ++nt)
                #pragma unroll
                for (int mt = 0; mt < 4; ++mt)
                    facc[mt][nt] = __builtin_amdgcn_mfma_f32_16x16x32_bf16(A[mt], Bv[ksl * 2 + nt], facc[mt][nt], 0, 0, 0);
        }
    }

    const float bcol0 = bias[nb2 + l16];
    const float bcol1 = bias[nb2 + 16 + l16];
    #pragma unroll
    for (int mt = 0; mt < 4; ++mt)
        #pragma unroll
        for (int r = 0; r < 4; ++r) {
            const size_t row = rowBase + mt * 16 + kg * 4 + r;
            out[row * 128 + nb2 + l16]      = facc[mt][0][r] + bcol0;
            out[row * 128 + nb2 + 16 + l16] = facc[mt][1][r] + bcol1;
        }
}

extern "C" void kernel_launch(void* const* d_in, const int* in_sizes, int n_in,
                              void* d_out, int out_size, void* d_ws, size_t ws_size,
                              hipStream_t stream)
{
    const float* x      = (const float*)d_in[0];
    const float* inph   = (const float*)d_in[1];
    const float* mzi1   = (const float*)d_in[2];
    const float* outph1 = (const float*)d_in[3];
    const float* alpha1 = (const float*)d_in[4];
    const float* beta1  = (const float*)d_in[5];
    const float* mzi2   = (const float*)d_in[6];
    const float* outph2 = (const float*)d_in[7];
    const float* alpha2 = (const float*)d_in[8];
    const float* beta2  = (const float*)d_in[9];
    const float* mzi3   = (const float*)d_in[10];
    const float* outph3 = (const float*)d_in[11];
    const float* W      = (const float*)d_in[12];
    const float* bias   = (const float*)d_in[13];

    const int B = in_sizes[0] / 128;

    // ws layout
    float4* trig = (float4*)d_ws;                          // 3*128*64*16 = 393216 B
    u16* P1 = (u16*)((char*)d_ws + 393216);                // 65536 B
    u16* P2 = P1 + 32768;                                  // 131072 B
    u16* P3 = P2 + 65536;                                  // 131072 B
    u16* P4 = P3 + 65536;                                  // 65536 B

    prep_trig_kernel<<<512, 128, 0, stream>>>(mzi1, mzi2, mzi3, W, trig, P4);
    build_pack_kernel<<<384, 64, 0, stream>>>(inph, outph1, outph2, outph3, trig, P1, P2, P3);
    ficonn_mfma_kernel<<<B / 64, 256, 0, stream>>>(
        x, P1, P2, P3, P4, alpha1, beta1, alpha2, beta2, bias, (float*)d_out);
}